// Round 7
// baseline (55.905 us; speedup 1.0000x reference)
//
#include <hip/hip_runtime.h>

#define NG 20000
#define NB 1024

typedef float v4f __attribute__((ext_vector_type(4)));
typedef float v2f __attribute__((ext_vector_type(2)));

constexpr int THREADS = 128;            // 2 waves
constexpr int GPT = 2;                  // genes per thread (both techs)
constexpr int GPB = THREADS * GPT;      // 256 genes per block
constexpr int NGB = (NG + GPB - 1) / GPB;   // 79 gene chunks (tail in gb=78)
constexpr int BB  = 32;                 // batches per block
constexpr int NBB = NB / BB;            // 32

// Fully-resident single pass: 2528 blocks x 2 waves, launch_bounds(128,5)
// -> 10 blocks/CU resident -> zero dispatch tail. Each thread: 2 genes,
// BOTH techs, 58 param floats in registers, no cross-lane ops, full-wave
// 8B loads (2x512B segments/wave) and full-wave 8B stores. Depth-4 NT
// pipeline keeps 4KB/wave outstanding.
__global__ __launch_bounds__(THREADS, 5)
void cgm_kernel(const float* __restrict__ x,
                const float* __restrict__ w1,
                const float* __restrict__ b1,
                const float* __restrict__ w2,
                const float* __restrict__ b2,
                const float* __restrict__ wg,
                const float* __restrict__ bg,
                float* __restrict__ out)
{
    const int bid = (int)blockIdx.x;    // 0..2527
    const int gb  = bid % NGB;          // 0..78
    const int bb  = bid / NGB;          // 0..31

    const int gbase = gb * GPB + (int)threadIdx.x * GPT;
    if (gbase >= NG) return;            // tail threads in gb==78 only

    // ---- per-thread params in registers (2 genes x 2 techs) ----
    v4f W1[2][2], B1[2][2], W2[2][2];   // [tech][gene_j]
    float B2v[2][2];
    #pragma unroll
    for (int t = 0; t < 2; ++t) {
        const size_t r0 = (size_t)t * NG + (size_t)gbase;
        #pragma unroll
        for (int g = 0; g < 2; ++g) {
            W1[t][g]  = *(const v4f*)(w1 + (r0 + g) * 4);
            B1[t][g]  = *(const v4f*)(b1 + (r0 + g) * 4);
            W2[t][g]  = *(const v4f*)(w2 + (r0 + g) * 4);
            B2v[t][g] = b2[r0 + g];
        }
    }
    const v4f wgv = *(const v4f*)(wg + (size_t)gbase * 2);  // g0t0 g0t1 g1t0 g1t1
    const v2f bgv = *(const v2f*)(bg + gbase);

    const float* xb = x + (size_t)gbase;
    float*       ob = out + (size_t)gbase;
    const int b_lo = bb * BB;

    auto load1 = [&](v2f* dst, int bi) {   // dst[0]=tech0, dst[1]=tech1
        const float* xr = xb + (size_t)(b_lo + bi) * (2 * NG);
        dst[0] = __builtin_nontemporal_load((const v2f*)xr);
        dst[1] = __builtin_nontemporal_load((const v2f*)(xr + NG));
    };
    auto proc1 = [&](const v2f* xv, int bi) {
        float s[2][2];
        #pragma unroll
        for (int t = 0; t < 2; ++t) {
            #pragma unroll
            for (int g = 0; g < 2; ++g) {
                const float v = xv[t][g];
                float h, acc = 0.f;
                h = fmaxf(fmaf(v, W1[t][g].x, B1[t][g].x), 0.f); acc = fmaf(h, W2[t][g].x, acc);
                h = fmaxf(fmaf(v, W1[t][g].y, B1[t][g].y), 0.f); acc = fmaf(h, W2[t][g].y, acc);
                h = fmaxf(fmaf(v, W1[t][g].z, B1[t][g].z), 0.f); acc = fmaf(h, W2[t][g].z, acc);
                h = fmaxf(fmaf(v, W1[t][g].w, B1[t][g].w), 0.f); acc = fmaf(h, W2[t][g].w, acc);
                s[t][g] = fmaxf(acc + B2v[t][g], 0.f);
            }
        }
        v2f o;
        o.x = fmaxf(fmaf(s[0][0], wgv.x, fmaf(s[1][0], wgv.y, bgv.x)), 0.f);
        o.y = fmaxf(fmaf(s[0][1], wgv.z, fmaf(s[1][1], wgv.w, bgv.y)), 0.f);
        __builtin_nontemporal_store(o, (v2f*)(ob + (size_t)(b_lo + bi) * NG));
    };

    v2f A[2][2], B[2][2];               // [slot][tech]
    load1(A[0], 0); load1(A[1], 1);
    load1(B[0], 2); load1(B[1], 3);
    #pragma unroll
    for (int bi = 0; bi < BB; bi += 4) {
        proc1(A[0], bi);     proc1(A[1], bi + 1);
        if (bi + 4 < BB) { load1(A[0], bi + 4); load1(A[1], bi + 5); }
        proc1(B[0], bi + 2); proc1(B[1], bi + 3);
        if (bi + 6 < BB) { load1(B[0], bi + 6); load1(B[1], bi + 7); }
    }
}

extern "C" void kernel_launch(void* const* d_in, const int* in_sizes, int n_in,
                              void* d_out, int out_size, void* d_ws, size_t ws_size,
                              hipStream_t stream) {
    const float* x  = (const float*)d_in[0];
    const float* w1 = (const float*)d_in[1];
    const float* b1 = (const float*)d_in[2];
    const float* w2 = (const float*)d_in[3];
    const float* b2 = (const float*)d_in[4];
    const float* wg = (const float*)d_in[5];
    const float* bg = (const float*)d_in[6];
    float* out = (float*)d_out;

    dim3 grid(NGB * NBB);   // 79 * 32 = 2528 blocks (~10/CU, fully resident)
    cgm_kernel<<<grid, THREADS, 0, stream>>>(x, w1, b1, w2, b2, wg, bg, out);
}

// Round 8
// 51.375 us; speedup vs baseline: 1.0882x; 1.0882x over previous
//
#include <hip/hip_runtime.h>

#define NG 20000
#define NB 1024

typedef float v4f __attribute__((ext_vector_type(4)));

constexpr int THREADS = 256;            // 4 waves
constexpr int GENES_PER_BLOCK = 512;    // 128 gene-lanes * 4 genes
constexpr int NGB = 40;                 // ceil(20000/512)
constexpr int BB  = 32;                 // batches per block
constexpr int NBB = NB / BB;            // 32
constexpr int GB_PER_XCD = NGB / 8;     // 5 gene-chunks per XCD

// R6 (best: 53.0us) with ONE change: stores are plain (not nontemporal).
// Measured WRITE_SIZE was 2.5-4.6x the 82MB output with NT stores ->
// hypothesis: nt bypasses L2 write-combining, causing partial-burst RMW
// amplification at the MC. Plain stores write-combine in L2, evict once.
// NT loads kept (x is strictly single-use streaming).
__global__ __launch_bounds__(THREADS, 4)
void cgm_kernel(const float* __restrict__ x,
                const float* __restrict__ w1,
                const float* __restrict__ b1,
                const float* __restrict__ w2,
                const float* __restrict__ b2,
                const float* __restrict__ wg,
                const float* __restrict__ bg,
                float* __restrict__ out)
{
    // XCD mapping: each XCD owns 5 gene-chunks x 32 batch-chunks.
    const int bid = (int)blockIdx.x;          // 0..1279
    const int xcd = bid & 7;
    const int j   = bid >> 3;                 // 0..159
    const int gb  = xcd * GB_PER_XCD + (j / NBB);   // 0..39
    const int bb  = j % NBB;                  // 0..31

    const int lane = (int)threadIdx.x & 63;
    const int wv   = (int)threadIdx.x >> 6;
    const int t    = lane >> 5;               // tech 0/1 per half-wave
    const int gl   = wv * 32 + (lane & 31);   // gene-lane 0..127
    const int gbase = gb * GENES_PER_BLOCK + gl * 4;
    if (gbase >= NG) return;                  // tail (gb==39): partners stay paired

    // ---- per-thread params in registers (own tech only) ----
    v4f W1[4], B1[4], W2[4];
    float B2v[4];
    const size_t r0 = (size_t)t * NG + (size_t)gbase;
    #pragma unroll
    for (int g = 0; g < 4; ++g) {
        W1[g]  = *(const v4f*)(w1 + (r0 + g) * 4);
        B1[g]  = *(const v4f*)(b1 + (r0 + g) * 4);
        W2[g]  = *(const v4f*)(w2 + (r0 + g) * 4);
        B2v[g] = b2[r0 + g];
    }
    const v4f wgA = *(const v4f*)(wg + (size_t)gbase * 2);      // g0t0 g0t1 g1t0 g1t1
    const v4f wgB = *(const v4f*)(wg + (size_t)gbase * 2 + 4);  // g2t0 g2t1 g3t0 g3t1
    const v4f bgv = *(const v4f*)(bg + gbase);

    const float* xbase = x + (size_t)t * NG + (size_t)gbase;
    float*       obase = out + (size_t)gbase;
    const int b_lo = bb * BB;

    auto load4 = [&](v4f* dst, int bi) {
        #pragma unroll
        for (int k = 0; k < 4; ++k)
            dst[k] = __builtin_nontemporal_load(
                (const v4f*)(xbase + (size_t)(b_lo + bi + k) * (2 * NG)));
    };
    auto proc1 = [&](v4f xv, int b_abs) {
        float s[4];
        #pragma unroll
        for (int g = 0; g < 4; ++g) {
            const float v = xv[g];
            float h, acc = 0.f;
            h = fmaxf(fmaf(v, W1[g].x, B1[g].x), 0.f); acc = fmaf(h, W2[g].x, acc);
            h = fmaxf(fmaf(v, W1[g].y, B1[g].y), 0.f); acc = fmaf(h, W2[g].y, acc);
            h = fmaxf(fmaf(v, W1[g].z, B1[g].z), 0.f); acc = fmaf(h, W2[g].z, acc);
            h = fmaxf(fmaf(v, W1[g].w, B1[g].w), 0.f); acc = fmaf(h, W2[g].w, acc);
            s[g] = fmaxf(acc + B2v[g], 0.f);
        }
        float so[4];
        #pragma unroll
        for (int g = 0; g < 4; ++g) so[g] = __shfl_xor(s[g], 32, 64);
        if (t == 0) {
            v4f o;
            o.x = fmaxf(fmaf(s[0], wgA.x, fmaf(so[0], wgA.y, bgv.x)), 0.f);
            o.y = fmaxf(fmaf(s[1], wgA.z, fmaf(so[1], wgA.w, bgv.y)), 0.f);
            o.z = fmaxf(fmaf(s[2], wgB.x, fmaf(so[2], wgB.y, bgv.z)), 0.f);
            o.w = fmaxf(fmaf(s[3], wgB.z, fmaf(so[3], wgB.w, bgv.w)), 0.f);
            *(v4f*)(obase + (size_t)b_abs * NG) = o;   // plain store (write-combine in L2)
        }
    };

    v4f A[4], B[4];
    load4(A, 0);
    load4(B, 4);
    #pragma unroll
    for (int bi = 0; bi < BB; bi += 8) {
        #pragma unroll
        for (int k = 0; k < 4; ++k) proc1(A[k], b_lo + bi + k);
        if (bi + 8 < BB) load4(A, bi + 8);
        #pragma unroll
        for (int k = 0; k < 4; ++k) proc1(B[k], b_lo + bi + 4 + k);
        if (bi + 12 < BB) load4(B, bi + 12);
    }
}

extern "C" void kernel_launch(void* const* d_in, const int* in_sizes, int n_in,
                              void* d_out, int out_size, void* d_ws, size_t ws_size,
                              hipStream_t stream) {
    const float* x  = (const float*)d_in[0];
    const float* w1 = (const float*)d_in[1];
    const float* b1 = (const float*)d_in[2];
    const float* w2 = (const float*)d_in[3];
    const float* b2 = (const float*)d_in[4];
    const float* wg = (const float*)d_in[5];
    const float* bg = (const float*)d_in[6];
    float* out = (float*)d_out;

    dim3 grid(NGB * NBB);   // 40 * 32 = 1280 blocks
    cgm_kernel<<<grid, THREADS, 0, stream>>>(x, w1, b1, w2, b2, wg, bg, out);
}

// Round 9
// 45.215 us; speedup vs baseline: 1.2364x; 1.1362x over previous
//
#include <hip/hip_runtime.h>

#define NG 20000
#define NB 1024

typedef float v4f __attribute__((ext_vector_type(4)));

constexpr int THREADS = 256;            // 4 waves
constexpr int GENES_PER_BLOCK = 512;    // 128 gene-lanes * 4 genes
constexpr int NGB = 40;                 // ceil(20000/512)
constexpr int BB  = 32;                 // batches per block
constexpr int NBB = NB / BB;            // 32
constexpr int GB_PER_XCD = NGB / 8;     // 5 gene-chunks per XCD

// R8 (best: 51.4us) with ONE change: x loads are plain (not nontemporal).
// A/B: NT loads skip L2 allocate; theory is they also skip L2/MSHR request
// batching that recovers DRAM row locality for our 512B-segment gather.
// Risk: plain x stream may evict the ~300KB/XCD L2-resident param set.
__global__ __launch_bounds__(THREADS, 4)
void cgm_kernel(const float* __restrict__ x,
                const float* __restrict__ w1,
                const float* __restrict__ b1,
                const float* __restrict__ w2,
                const float* __restrict__ b2,
                const float* __restrict__ wg,
                const float* __restrict__ bg,
                float* __restrict__ out)
{
    // XCD mapping: each XCD owns 5 gene-chunks x 32 batch-chunks.
    const int bid = (int)blockIdx.x;          // 0..1279
    const int xcd = bid & 7;
    const int j   = bid >> 3;                 // 0..159
    const int gb  = xcd * GB_PER_XCD + (j / NBB);   // 0..39
    const int bb  = j % NBB;                  // 0..31

    const int lane = (int)threadIdx.x & 63;
    const int wv   = (int)threadIdx.x >> 6;
    const int t    = lane >> 5;               // tech 0/1 per half-wave
    const int gl   = wv * 32 + (lane & 31);   // gene-lane 0..127
    const int gbase = gb * GENES_PER_BLOCK + gl * 4;
    if (gbase >= NG) return;                  // tail (gb==39): partners stay paired

    // ---- per-thread params in registers (own tech only) ----
    v4f W1[4], B1[4], W2[4];
    float B2v[4];
    const size_t r0 = (size_t)t * NG + (size_t)gbase;
    #pragma unroll
    for (int g = 0; g < 4; ++g) {
        W1[g]  = *(const v4f*)(w1 + (r0 + g) * 4);
        B1[g]  = *(const v4f*)(b1 + (r0 + g) * 4);
        W2[g]  = *(const v4f*)(w2 + (r0 + g) * 4);
        B2v[g] = b2[r0 + g];
    }
    const v4f wgA = *(const v4f*)(wg + (size_t)gbase * 2);      // g0t0 g0t1 g1t0 g1t1
    const v4f wgB = *(const v4f*)(wg + (size_t)gbase * 2 + 4);  // g2t0 g2t1 g3t0 g3t1
    const v4f bgv = *(const v4f*)(bg + gbase);

    const float* xbase = x + (size_t)t * NG + (size_t)gbase;
    float*       obase = out + (size_t)gbase;
    const int b_lo = bb * BB;

    auto load4 = [&](v4f* dst, int bi) {
        #pragma unroll
        for (int k = 0; k < 4; ++k)
            dst[k] = *(const v4f*)(xbase + (size_t)(b_lo + bi + k) * (2 * NG));  // plain load
    };
    auto proc1 = [&](v4f xv, int b_abs) {
        float s[4];
        #pragma unroll
        for (int g = 0; g < 4; ++g) {
            const float v = xv[g];
            float h, acc = 0.f;
            h = fmaxf(fmaf(v, W1[g].x, B1[g].x), 0.f); acc = fmaf(h, W2[g].x, acc);
            h = fmaxf(fmaf(v, W1[g].y, B1[g].y), 0.f); acc = fmaf(h, W2[g].y, acc);
            h = fmaxf(fmaf(v, W1[g].z, B1[g].z), 0.f); acc = fmaf(h, W2[g].z, acc);
            h = fmaxf(fmaf(v, W1[g].w, B1[g].w), 0.f); acc = fmaf(h, W2[g].w, acc);
            s[g] = fmaxf(acc + B2v[g], 0.f);
        }
        float so[4];
        #pragma unroll
        for (int g = 0; g < 4; ++g) so[g] = __shfl_xor(s[g], 32, 64);
        if (t == 0) {
            v4f o;
            o.x = fmaxf(fmaf(s[0], wgA.x, fmaf(so[0], wgA.y, bgv.x)), 0.f);
            o.y = fmaxf(fmaf(s[1], wgA.z, fmaf(so[1], wgA.w, bgv.y)), 0.f);
            o.z = fmaxf(fmaf(s[2], wgB.x, fmaf(so[2], wgB.y, bgv.z)), 0.f);
            o.w = fmaxf(fmaf(s[3], wgB.z, fmaf(so[3], wgB.w, bgv.w)), 0.f);
            *(v4f*)(obase + (size_t)b_abs * NG) = o;   // plain store (R8 win)
        }
    };

    v4f A[4], B[4];
    load4(A, 0);
    load4(B, 4);
    #pragma unroll
    for (int bi = 0; bi < BB; bi += 8) {
        #pragma unroll
        for (int k = 0; k < 4; ++k) proc1(A[k], b_lo + bi + k);
        if (bi + 8 < BB) load4(A, bi + 8);
        #pragma unroll
        for (int k = 0; k < 4; ++k) proc1(B[k], b_lo + bi + 4 + k);
        if (bi + 12 < BB) load4(B, bi + 12);
    }
}

extern "C" void kernel_launch(void* const* d_in, const int* in_sizes, int n_in,
                              void* d_out, int out_size, void* d_ws, size_t ws_size,
                              hipStream_t stream) {
    const float* x  = (const float*)d_in[0];
    const float* w1 = (const float*)d_in[1];
    const float* b1 = (const float*)d_in[2];
    const float* w2 = (const float*)d_in[3];
    const float* b2 = (const float*)d_in[4];
    const float* wg = (const float*)d_in[5];
    const float* bg = (const float*)d_in[6];
    float* out = (float*)d_out;

    dim3 grid(NGB * NBB);   // 40 * 32 = 1280 blocks
    cgm_kernel<<<grid, THREADS, 0, stream>>>(x, w1, b1, w2, b2, wg, bg, out);
}